// Round 2
// baseline (2800.380 us; speedup 1.0000x reference)
//
#include <hip/hip_runtime.h>
#include <cstdint>
#include <cstddef>

typedef __bf16 bf16_t;
typedef __attribute__((ext_vector_type(8))) __bf16 bf16x8;
typedef __attribute__((ext_vector_type(4))) __bf16 bf16x4;
typedef __attribute__((ext_vector_type(4))) float f32x4;

#define TSTEPS 20

static __device__ __forceinline__ f32x4 mfma_(bf16x8 a, bf16x8 b, f32x4 c) {
    return __builtin_amdgcn_mfma_f32_16x16x32_bf16(a, b, c, 0, 0, 0);
}
static __device__ __forceinline__ float sig_(float x) {
    return __builtin_amdgcn_rcpf(1.0f + __expf(-x));
}
static __device__ __forceinline__ float tanh_(float x) {
    return 2.0f * __builtin_amdgcn_rcpf(1.0f + __expf(-2.0f * x)) - 1.0f;
}
// element-index swizzle for [row][256] bf16 LDS tiles: spreads rows across
// 16B slots so 16-lane column reads are 2-way (free) instead of 16-way.
static __device__ __forceinline__ int swz(int row, int k) {
    return ((row << 8) + k) ^ ((row & 7) << 3);
}

// ---------------------------------------------------------------------------
// Pack row-major fp32 weights [K][cols] into MFMA B-fragment tiles (bf16).
// Tile = nt*ktiles + kt; within tile lane holds 8 bf16:
//   elem(lane,e) = src[kt*32 + (lane>>4)*8 + e][nt*16 + (lane&15)]
// ---------------------------------------------------------------------------
__global__ void pack_b_kernel(const float* __restrict__ srcA, int ldA,
                              const float* __restrict__ srcB, int ldB,
                              int split, int ntiles, int ktiles,
                              bf16_t* __restrict__ dst)
{
    int tid = blockIdx.x * blockDim.x + threadIdx.x;
    int total = ntiles * ktiles * 64;
    if (tid >= total) return;
    int lane = tid & 63;
    int tile = tid >> 6;
    int kt = tile % ktiles;
    int nt = tile / ktiles;
    int c  = (nt << 4) + (lane & 15);
    int k0 = (kt << 5) + ((lane >> 4) << 3);
    bf16x8 v;
    #pragma unroll
    for (int e = 0; e < 8; ++e) {
        int k = k0 + e;
        float x;
        if (c < split) x = srcA[(size_t)k * ldA + c];
        else           x = srcB[(size_t)k * ldB + (c - split)];
        v[e] = (bf16_t)x;
    }
    *reinterpret_cast<bf16x8*>(&dst[(size_t)tid * 8]) = v;
}

// ---------------------------------------------------------------------------
// Persistent 2-layer LSTM scan. BM=32 rows/block, grid=256, 8 waves (512 thr).
// Wave wv owns h-column tiles {wv*2, wv*2+1}; gate tile ntg = g*16 + wv*2 + ht.
// Layer 1 is a K=320 GEMM: [z_cat | h1_old] @ [W1 ; U1]  (z frags persistent).
// h1/h2 in LDS (bf16, double-buffered, swizzled); c1/c2 in fp32 VGPRs.
// ---------------------------------------------------------------------------
__global__ __launch_bounds__(512, 2)
void lstm_scan_kernel(const float* __restrict__ z1, const float* __restrict__ z2,
                      const float* __restrict__ b1, const float* __restrict__ b2,
                      const bf16x8* __restrict__ W1f, const bf16x8* __restrict__ U1f,
                      const bf16x8* __restrict__ B2f,
                      float* __restrict__ out)
{
    __shared__ alignas(16) bf16_t h1buf[2 * 32 * 256];  // 32KB ping-pong
    __shared__ alignas(16) bf16_t h2buf[2 * 32 * 256];  // 32KB ping-pong
    __shared__ alignas(16) bf16_t zc[32 * 64];          // 4KB z_cat

    const int tid  = threadIdx.x;
    const int lane = tid & 63;
    const int wv   = tid >> 6;      // 0..7
    const int l15  = lane & 15;
    const int lq   = lane >> 4;     // 0..3
    const int b0   = blockIdx.x << 5;

    // zero h buffers
    {
        bf16x8 z8;
        #pragma unroll
        for (int j = 0; j < 8; ++j) z8[j] = (bf16_t)0.0f;
        bf16x8* h1v = reinterpret_cast<bf16x8*>(h1buf);
        bf16x8* h2v = reinterpret_cast<bf16x8*>(h2buf);
        for (int i = tid; i < 2048; i += 512) { h1v[i] = z8; h2v[i] = z8; }
    }
    // stage z_cat as bf16 [32 rows][64 k]
    for (int i = tid; i < 2048; i += 512) {
        int r = i >> 6, k = i & 63;
        float v = (k < 32) ? z1[(size_t)(b0 + r) * 32 + k]
                           : z2[(size_t)(b0 + r) * 32 + (k - 32)];
        zc[i] = (bf16_t)v;
    }
    __syncthreads();

    // persistent z_cat A-fragments (step-invariant): zf[mt][kt]
    bf16x8 zf[2][2];
    #pragma unroll
    for (int mt = 0; mt < 2; ++mt)
        #pragma unroll
        for (int kt = 0; kt < 2; ++kt)
            zf[mt][kt] = *reinterpret_cast<const bf16x8*>(
                &zc[((mt << 4) + l15) * 64 + (kt << 5) + (lq << 3)]);

    // biases in C-fragment layout (scalar per thread per (ht,g))
    float b1r[2][4], b2r[2][4];
    #pragma unroll
    for (int ht = 0; ht < 2; ++ht)
        #pragma unroll
        for (int g = 0; g < 4; ++g) {
            const int ntg = (g << 4) + (wv << 1) + ht;
            b1r[ht][g] = b1[(ntg << 4) + l15];
            b2r[ht][g] = b2[(ntg << 4) + l15];
        }

    f32x4 c1[2][2], c2[2][2];   // [mt][ht]
    #pragma unroll
    for (int mt = 0; mt < 2; ++mt)
        #pragma unroll
        for (int ht = 0; ht < 2; ++ht) {
            c1[mt][ht] = (f32x4){0.f, 0.f, 0.f, 0.f};
            c2[mt][ht] = (f32x4){0.f, 0.f, 0.f, 0.f};
        }

    const size_t outbase = (size_t)b0 * (TSTEPS * 256);

    for (int t = 0; t < TSTEPS; ++t) {
        const int cur = (t & 1) << 13;
        const int nxt = 8192 - cur;

        f32x4 ag[2][2][4];   // [ht][mt][g]
        #pragma unroll
        for (int ht = 0; ht < 2; ++ht)
            #pragma unroll
            for (int g = 0; g < 4; ++g) {
                const float b = b1r[ht][g];
                ag[ht][0][g] = (f32x4){b, b, b, b};
                ag[ht][1][g] = (f32x4){b, b, b, b};
            }

        // ---- layer 1: gates = b1 + [z|h1_old] @ [W1;U1] ----
        {
            bf16x8 af[2][8];
            #pragma unroll
            for (int mt = 0; mt < 2; ++mt)
                #pragma unroll
                for (int kt = 0; kt < 8; ++kt) {
                    int row = (mt << 4) + l15;
                    af[mt][kt] = *reinterpret_cast<const bf16x8*>(
                        &h1buf[cur + swz(row, (kt << 5) + (lq << 3))]);
                }
            #pragma unroll
            for (int ht = 0; ht < 2; ++ht)
                #pragma unroll
                for (int g = 0; g < 4; ++g) {
                    const int ntg = (g << 4) + (wv << 1) + ht;
                    const bf16x8* wz = W1f + ((ntg << 1) << 6) + lane;
                    #pragma unroll
                    for (int kt = 0; kt < 2; ++kt) {
                        bf16x8 w = wz[kt << 6];
                        ag[ht][0][g] = mfma_(zf[0][kt], w, ag[ht][0][g]);
                        ag[ht][1][g] = mfma_(zf[1][kt], w, ag[ht][1][g]);
                    }
                    const bf16x8* wu = U1f + ((ntg << 3) << 6) + lane;
                    #pragma unroll
                    for (int kt = 0; kt < 8; ++kt) {
                        bf16x8 w = wu[kt << 6];
                        ag[ht][0][g] = mfma_(af[0][kt], w, ag[ht][0][g]);
                        ag[ht][1][g] = mfma_(af[1][kt], w, ag[ht][1][g]);
                    }
                }
        }
        // epilogue layer 1 -> h1_new, c1
        #pragma unroll
        for (int ht = 0; ht < 2; ++ht) {
            const int colb = (((wv << 1) + ht) << 4) + l15;
            #pragma unroll
            for (int mt = 0; mt < 2; ++mt)
                #pragma unroll
                for (int j = 0; j < 4; ++j) {
                    float iv = sig_(ag[ht][mt][0][j]);
                    float fv = sig_(ag[ht][mt][1][j]);
                    float gv = tanh_(ag[ht][mt][2][j]);
                    float ov = sig_(ag[ht][mt][3][j]);
                    float cn = fv * c1[mt][ht][j] + iv * gv;
                    c1[mt][ht][j] = cn;
                    float hn = ov * tanh_(cn);
                    int row = (mt << 4) + (lq << 2) + j;
                    h1buf[nxt + swz(row, colb)] = (bf16_t)hn;
                }
        }
        __syncthreads();

        // ---- layer 2: gates = b2 + h1_new @ W2 + h2_old @ U2 ----
        #pragma unroll
        for (int ht = 0; ht < 2; ++ht)
            #pragma unroll
            for (int g = 0; g < 4; ++g) {
                const float b = b2r[ht][g];
                ag[ht][0][g] = (f32x4){b, b, b, b};
                ag[ht][1][g] = (f32x4){b, b, b, b};
            }
        {
            bf16x8 af[2][8];
            // pass A: h1_new @ W2
            #pragma unroll
            for (int mt = 0; mt < 2; ++mt)
                #pragma unroll
                for (int kt = 0; kt < 8; ++kt) {
                    int row = (mt << 4) + l15;
                    af[mt][kt] = *reinterpret_cast<const bf16x8*>(
                        &h1buf[nxt + swz(row, (kt << 5) + (lq << 3))]);
                }
            #pragma unroll
            for (int ht = 0; ht < 2; ++ht)
                #pragma unroll
                for (int g = 0; g < 4; ++g) {
                    const int ntg = (g << 4) + (wv << 1) + ht;
                    const bf16x8* w2 = B2f + ((ntg << 3) << 6) + lane;
                    #pragma unroll
                    for (int kt = 0; kt < 8; ++kt) {
                        bf16x8 w = w2[kt << 6];
                        ag[ht][0][g] = mfma_(af[0][kt], w, ag[ht][0][g]);
                        ag[ht][1][g] = mfma_(af[1][kt], w, ag[ht][1][g]);
                    }
                }
            // pass B: h2_old @ U2 (reuse af regs)
            #pragma unroll
            for (int mt = 0; mt < 2; ++mt)
                #pragma unroll
                for (int kt = 0; kt < 8; ++kt) {
                    int row = (mt << 4) + l15;
                    af[mt][kt] = *reinterpret_cast<const bf16x8*>(
                        &h2buf[cur + swz(row, (kt << 5) + (lq << 3))]);
                }
            #pragma unroll
            for (int ht = 0; ht < 2; ++ht)
                #pragma unroll
                for (int g = 0; g < 4; ++g) {
                    const int ntg = (g << 4) + (wv << 1) + ht;
                    const bf16x8* u2 = B2f + (((64 + ntg) << 3) << 6) + lane;
                    #pragma unroll
                    for (int kt = 0; kt < 8; ++kt) {
                        bf16x8 w = u2[kt << 6];
                        ag[ht][0][g] = mfma_(af[0][kt], w, ag[ht][0][g]);
                        ag[ht][1][g] = mfma_(af[1][kt], w, ag[ht][1][g]);
                    }
                }
        }
        // epilogue layer 2 -> h2_new, c2, out (nontemporal: don't thrash L2)
        #pragma unroll
        for (int ht = 0; ht < 2; ++ht) {
            const int colb = (((wv << 1) + ht) << 4) + l15;
            #pragma unroll
            for (int mt = 0; mt < 2; ++mt)
                #pragma unroll
                for (int j = 0; j < 4; ++j) {
                    float iv = sig_(ag[ht][mt][0][j]);
                    float fv = sig_(ag[ht][mt][1][j]);
                    float gv = tanh_(ag[ht][mt][2][j]);
                    float ov = sig_(ag[ht][mt][3][j]);
                    float cn = fv * c2[mt][ht][j] + iv * gv;
                    c2[mt][ht][j] = cn;
                    float hn = ov * tanh_(cn);
                    int row = (mt << 4) + (lq << 2) + j;
                    h2buf[nxt + swz(row, colb)] = (bf16_t)hn;
                    __builtin_nontemporal_store(
                        hn, &out[outbase + (size_t)row * (TSTEPS * 256) + t * 256 + colb]);
                }
        }
        __syncthreads();
    }
}

// ---------------------------------------------------------------------------
// Projection: stage 64 rows of `out` (fp32) through LDS (coalesced f32x4),
// MFMA against packed [Wmu|Wlv], fused epilogue with swapped-args reparam.
// ---------------------------------------------------------------------------
__global__ __launch_bounds__(256)
void proj_kernel(const float* __restrict__ outp, const float* __restrict__ eps,
                 const float* __restrict__ bmu, const float* __restrict__ blv,
                 const bf16x8* __restrict__ Wpf,
                 float* __restrict__ xmu, float* __restrict__ xlv, float* __restrict__ xsm)
{
    __shared__ alignas(16) bf16_t sbuf[64 * 256];   // 32KB

    const int tid = threadIdx.x, lane = tid & 63, wv = tid >> 6;
    const int l15 = lane & 15, lq = lane >> 4;
    const size_t r0 = (size_t)blockIdx.x * 64;

    // stage: coalesced fp32 reads -> bf16 LDS (swizzled)
    const float* src = &outp[r0 * 256];
    #pragma unroll
    for (int it = 0; it < 16; ++it) {
        int e = (it << 10) + (tid << 2);
        int row = e >> 8, col = e & 255;
        f32x4 v = *reinterpret_cast<const f32x4*>(&src[e]);
        bf16x4 b;
        #pragma unroll
        for (int j = 0; j < 4; ++j) b[j] = (bf16_t)v[j];
        *reinterpret_cast<bf16x4*>(&sbuf[swz(row, col)]) = b;
    }
    __syncthreads();

    // wave wv owns rows [wv*16, wv*16+16)
    bf16x8 af[8];
    #pragma unroll
    for (int kt = 0; kt < 8; ++kt) {
        int row = (wv << 4) + l15;
        af[kt] = *reinterpret_cast<const bf16x8*>(
            &sbuf[swz(row, (kt << 5) + (lq << 3))]);
    }

    f32x4 acc[10];
    #pragma unroll
    for (int nt = 0; nt < 10; ++nt) acc[nt] = (f32x4){0.f, 0.f, 0.f, 0.f};

    #pragma unroll
    for (int nt = 0; nt < 10; ++nt) {
        const bf16x8* bp = Wpf + ((nt << 3) << 6) + lane;
        #pragma unroll
        for (int kt = 0; kt < 8; ++kt)
            acc[nt] = mfma_(af[kt], bp[kt << 6], acc[nt]);
    }

    #pragma unroll
    for (int nt = 0; nt < 5; ++nt) {
        const int col = (nt << 4) + l15;   // 0..79
        const float bm = bmu[col], bl = blv[col];
        #pragma unroll
        for (int j = 0; j < 4; ++j) {
            size_t row = r0 + (wv << 4) + (lq << 2) + j;
            float mu = acc[nt][j] + bm;
            float lv = acc[5 + nt][j] + bl;
            size_t o = row * 80 + col;
            float sm = eps[o] * __expf(0.5f * mu) + lv;
            __builtin_nontemporal_store(mu, &xmu[o]);
            __builtin_nontemporal_store(lv, &xlv[o]);
            __builtin_nontemporal_store(sm, &xsm[o]);
        }
    }
}

// ---------------------------------------------------------------------------
extern "C" void kernel_launch(void* const* d_in, const int* in_sizes, int n_in,
                              void* d_out, int out_size, void* d_ws, size_t ws_size,
                              hipStream_t stream) {
    const float* z1  = (const float*)d_in[1];
    const float* z2  = (const float*)d_in[2];
    const float* eps = (const float*)d_in[3];
    const float* W1  = (const float*)d_in[4];
    const float* U1  = (const float*)d_in[5];
    const float* b1  = (const float*)d_in[6];
    const float* W2  = (const float*)d_in[7];
    const float* U2  = (const float*)d_in[8];
    const float* b2  = (const float*)d_in[9];
    const float* Wmu = (const float*)d_in[10];
    const float* bmu = (const float*)d_in[11];
    const float* Wlv = (const float*)d_in[12];
    const float* blv = (const float*)d_in[13];

    float* out0 = (float*)d_out;
    const size_t N_OUT = (size_t)8192 * 20 * 256;
    const size_t N_F   = (size_t)8192 * 20 * 80;
    float* xmu = out0 + N_OUT;
    float* xlv = xmu + N_F;
    float* xsm = xlv + N_F;

    bf16_t* W1p = (bf16_t*)d_ws;            // 64*2*64*8  = 65536 elems
    bf16_t* U1p = W1p + 65536;              // 64*8*64*8  = 262144
    bf16_t* B2p = U1p + 262144;             // 2 * 262144
    bf16_t* Wpp = B2p + 524288;             // 10*8*64*8  = 40960

    pack_b_kernel<<<32, 256, 0, stream>>>(W1, 1024, W1, 1024, 1 << 30, 64, 2, W1p);
    pack_b_kernel<<<128, 256, 0, stream>>>(U1, 1024, U1, 1024, 1 << 30, 64, 8, U1p);
    pack_b_kernel<<<128, 256, 0, stream>>>(W2, 1024, W2, 1024, 1 << 30, 64, 8, B2p);
    pack_b_kernel<<<128, 256, 0, stream>>>(U2, 1024, U2, 1024, 1 << 30, 64, 8, B2p + 262144);
    pack_b_kernel<<<20, 256, 0, stream>>>(Wmu, 80, Wlv, 80, 80, 10, 8, Wpp);

    lstm_scan_kernel<<<256, 512, 0, stream>>>(z1, z2, b1, b2,
                                              (const bf16x8*)W1p, (const bf16x8*)U1p,
                                              (const bf16x8*)B2p, out0);
    proj_kernel<<<2560, 256, 0, stream>>>(out0, eps, bmu, blv,
                                          (const bf16x8*)Wpp, xmu, xlv, xsm);
}